// Round 5
// baseline (421.825 us; speedup 1.0000x reference)
//
#include <hip/hip_runtime.h>
#include <stdint.h>

#define T_DIM   8192
#define IN_DIM  4096
#define OUT_DIM 4096
#define RANK    8

typedef int v4i  __attribute__((ext_vector_type(4)));
typedef int v16i __attribute__((ext_vector_type(16)));

__device__ __forceinline__ void async_copy16(const void* g, void* l) {
  __builtin_amdgcn_global_load_lds(
      (const __attribute__((address_space(1))) void*)g,
      (__attribute__((address_space(3))) void*)l, 16, 0, 0);
}

// ---------------------------------------------------------------------------
// pack_w: weight int32 -> int8  (unchanged from R4)
// ---------------------------------------------------------------------------
__global__ __launch_bounds__(256) void pack_w(
    const int* __restrict__ w32, int8_t* __restrict__ w8)
{
  const int idx = blockIdx.x * 256 + threadIdx.x;
  const int4 v = ((const int4*)w32)[idx];
  char4 q;
  q.x = (signed char)v.x; q.y = (signed char)v.y;
  q.z = (signed char)v.z; q.w = (signed char)v.w;
  ((char4*)w8)[idx] = q;
}

// ---------------------------------------------------------------------------
// quant_x: 4 rows/block, lora_a loaded once per block  (unchanged from R4 —
// its -24us is banked; frozen for attribution)
// ---------------------------------------------------------------------------
#define QROWS 4
__global__ __launch_bounds__(256) void quant_x(
    const float* __restrict__ x, const float* __restrict__ lora_a,
    int8_t* __restrict__ x_i8, float* __restrict__ x_scale,
    float* __restrict__ xa)
{
  const int tid = threadIdx.x;
  const int wave = tid >> 6;
  const size_t row0 = (size_t)blockIdx.x * QROWS;
  __shared__ float redm[4][QROWS];
  __shared__ float redd[4][QROWS][RANK];

  const float4* xr = (const float4*)(x + row0 * IN_DIM);
  float4 xv[QROWS][4];
#pragma unroll
  for (int r = 0; r < QROWS; ++r)
#pragma unroll
    for (int c = 0; c < 4; ++c)
      xv[r][c] = xr[r * 1024 + c * 256 + tid];

  float am[QROWS];
#pragma unroll
  for (int r = 0; r < QROWS; ++r) {
    float m = 0.f;
#pragma unroll
    for (int c = 0; c < 4; ++c)
      m = fmaxf(m, fmaxf(fmaxf(fabsf(xv[r][c].x), fabsf(xv[r][c].y)),
                         fmaxf(fabsf(xv[r][c].z), fabsf(xv[r][c].w))));
    am[r] = m;
  }
#pragma unroll
  for (int off = 32; off > 0; off >>= 1)
#pragma unroll
    for (int r = 0; r < QROWS; ++r)
      am[r] = fmaxf(am[r], __shfl_xor(am[r], off, 64));
  if ((tid & 63) == 0)
#pragma unroll
    for (int r = 0; r < QROWS; ++r) redm[wave][r] = am[r];

  float dot[QROWS][RANK];
#pragma unroll
  for (int rk = 0; rk < RANK; ++rk) {
    const float4* ar = (const float4*)(lora_a + (size_t)rk * IN_DIM);
    float4 av[4];
#pragma unroll
    for (int c = 0; c < 4; ++c) av[c] = ar[c * 256 + tid];
#pragma unroll
    for (int r = 0; r < QROWS; ++r) {
      float s = 0.f;
#pragma unroll
      for (int c = 0; c < 4; ++c)
        s += xv[r][c].x * av[c].x + xv[r][c].y * av[c].y +
             xv[r][c].z * av[c].z + xv[r][c].w * av[c].w;
      dot[r][rk] = s;
    }
  }
#pragma unroll
  for (int off = 32; off > 0; off >>= 1)
#pragma unroll
    for (int r = 0; r < QROWS; ++r)
#pragma unroll
      for (int rk = 0; rk < RANK; ++rk)
        dot[r][rk] += __shfl_xor(dot[r][rk], off, 64);
  if ((tid & 63) == 0)
#pragma unroll
    for (int r = 0; r < QROWS; ++r)
#pragma unroll
      for (int rk = 0; rk < RANK; ++rk) redd[wave][r][rk] = dot[r][rk];
  __syncthreads();

#pragma unroll
  for (int r = 0; r < QROWS; ++r) {
    const float amax = fmaxf(fmaxf(redm[0][r], redm[1][r]),
                             fmaxf(redm[2][r], redm[3][r]));
    const float scale = amax * (1.0f / 127.0f);
    const float inv = 1.0f / fmaxf(scale, 1e-12f);
    char4* qout = (char4*)(x_i8 + (row0 + r) * IN_DIM);
#pragma unroll
    for (int c = 0; c < 4; ++c) {
      char4 q;
      q.x = (signed char)(int)rintf(xv[r][c].x * inv);
      q.y = (signed char)(int)rintf(xv[r][c].y * inv);
      q.z = (signed char)(int)rintf(xv[r][c].z * inv);
      q.w = (signed char)(int)rintf(xv[r][c].w * inv);
      qout[c * 256 + tid] = q;
    }
    if (tid == 0) x_scale[row0 + r] = scale;
  }
  if (tid < QROWS * RANK) {
    const int r = tid >> 3, rk = tid & 7;
    xa[(row0 + r) * RANK + rk] =
        redd[0][r][rk] + redd[1][r][rk] + redd[2][r][rk] + redd[3][r][rk];
  }
}

// ---------------------------------------------------------------------------
// GEMM: R1's PROVEN skeleton (3-buffer, SYNC(vmcnt(4)), stage-after-barrier,
// compiler-scheduled fine-grained lgkmcnt inside compute) restored verbatim;
// ONLY the MFMA shape changes: 16x16x64 -> 32x32x32 (4404 vs 3944 TOPS
// ceiling, half the MFMA instruction count; same 12 ds_read_b128/K-tile,
// same register budget: acc = 8 x v16i = 128 AGPR, 6 live v4i frags).
//
// Fragment map (32x32x32_i8): A/B lane l -> row/col = l&31, k-half = l>>5.
// LDS addr = row*64 + ((ks*2 + (l>>5)) ^ ((row>>1)&3))*16 ; since wr*128 and
// i*32 are multiples of 8, (row>>1)&3 == ((l&31)>>1)&3 — the staging-side
// swizzle (unchanged) matches. C/D: col = lane&31, row = (reg&3) + 8*(reg>>2)
// + 4*(lane>>5), reg in [0,16) [m74/m101, dtype-independent].
// ---------------------------------------------------------------------------
#define SYNC(n) do {                                      \
    asm volatile("s_waitcnt vmcnt(" #n ")" ::: "memory"); \
    __builtin_amdgcn_s_barrier();                         \
    __builtin_amdgcn_sched_barrier(0);                    \
  } while (0)

__device__ __forceinline__ void stage_tile(const int8_t* aSrc, const int8_t* bSrc,
                                           int8_t* Lbuf, int ldsOff) {
  async_copy16(aSrc,                          Lbuf + ldsOff);
  async_copy16(aSrc + (size_t)128 * IN_DIM,   Lbuf + 8192 + ldsOff);
  async_copy16(bSrc,                          Lbuf + 16384 + ldsOff);
  async_copy16(bSrc + (size_t)128 * IN_DIM,   Lbuf + 24576 + ldsOff);
}

__device__ __forceinline__ void compute_tile(const int8_t* Lbuf, int aBase, int bBase,
                                             int sw0, int sw1, v16i (&acc)[4][2]) {
#pragma unroll
  for (int ks = 0; ks < 2; ++ks) {
    const int s = ks ? sw1 : sw0;
    v4i aF[4], bF[2];
#pragma unroll
    for (int i = 0; i < 4; ++i) aF[i] = *(const v4i*)(Lbuf + aBase + i * 2048 + s);
#pragma unroll
    for (int j = 0; j < 2; ++j) bF[j] = *(const v4i*)(Lbuf + bBase + j * 2048 + s);
    __builtin_amdgcn_s_setprio(1);
#pragma unroll
    for (int i = 0; i < 4; ++i)
#pragma unroll
      for (int j = 0; j < 2; ++j)
        acc[i][j] = __builtin_amdgcn_mfma_i32_32x32x32_i8(aF[i], bF[j], acc[i][j], 0, 0, 0);
    __builtin_amdgcn_s_setprio(0);
  }
}

__global__ __launch_bounds__(512, 2) void gemm256_i8(
    const int8_t* __restrict__ A,       // x_i8 [T, IN]
    const int8_t* __restrict__ B,       // w8 [OUT, IN]
    const float* __restrict__ x_scale,  // [T]
    const float* __restrict__ w_scale,  // [OUT]
    const float* __restrict__ xa,       // [T, RANK] fp32
    const float* __restrict__ lora_b,   // [OUT, RANK]
    float* __restrict__ out)            // [T, OUT]
{
  __shared__ __align__(16) int8_t smem[3 * 32768];  // 96 KiB: 3 bufs x {A16K|B16K}
  const int tid = threadIdx.x;

  // XCD-bijective swizzle (512 % 8 == 0).
  const int orig = blockIdx.x;
  const int wgid = ((orig & 7) << 6) | (orig >> 3);
  const int by = wgid >> 4;   // 0..31
  const int bx = wgid & 15;   // 0..15
  const size_t arow0 = (size_t)by * 256;
  const size_t brow0 = (size_t)bx * 256;

  // staging (unchanged): row = tid>>2, slot = tid&3; slot pre-swizzled on the
  // GLOBAL source so the linear LDS write realizes lds[row][slot^((row>>1)&3)].
  const int r_l = tid >> 2;
  const int qsw = ((tid & 3) ^ ((r_l >> 1) & 3)) << 4;
  const int8_t* aSrc = A + (arow0 + r_l) * IN_DIM + qsw;
  const int8_t* bSrc = B + (brow0 + r_l) * IN_DIM + qsw;
  const int ldsOff = tid << 4;

  const int lane = tid & 63;
  const int wave = tid >> 6;
  const int wr = wave >> 2, wc = wave & 3;       // 2 x 4 wave grid, 128x64/wave
  const int r31 = lane & 31, khalf = lane >> 5;
  const int rsw = (r31 >> 1) & 3;
  const int sw0 = ((0 * 2 + khalf) ^ rsw) << 4;  // k-step 0 slot byte-offset
  const int sw1 = ((1 * 2 + khalf) ^ rsw) << 4;  // k-step 1 slot byte-offset
  const int aBase = (wr * 128 + r31) * 64;           // + i*2048 + s
  const int bBase = 16384 + (wc * 64 + r31) * 64;    // + j*2048 + s

  v16i acc[4][2];
#pragma unroll
  for (int i = 0; i < 4; ++i)
#pragma unroll
    for (int j = 0; j < 2; ++j)
#pragma unroll
      for (int e = 0; e < 16; ++e) acc[i][j][e] = 0;

  // prologue: tiles 0,1 in flight (8 loads)
  stage_tile(aSrc,      bSrc,      (int8_t*)smem,         ldsOff);
  stage_tile(aSrc + 64, bSrc + 64, (int8_t*)smem + 32768, ldsOff);

#pragma unroll 1
  for (int t = 0; t < 60; t += 3) {
    SYNC(4);
    stage_tile(aSrc + (t + 2) * 64, bSrc + (t + 2) * 64, (int8_t*)smem + 65536, ldsOff);
    compute_tile((const int8_t*)smem, aBase, bBase, sw0, sw1, acc);          // t   (buf0)
    SYNC(4);
    stage_tile(aSrc + (t + 3) * 64, bSrc + (t + 3) * 64, (int8_t*)smem, ldsOff);
    compute_tile((const int8_t*)smem + 32768, aBase, bBase, sw0, sw1, acc);  // t+1 (buf1)
    SYNC(4);
    stage_tile(aSrc + (t + 4) * 64, bSrc + (t + 4) * 64, (int8_t*)smem + 32768, ldsOff);
    compute_tile((const int8_t*)smem + 65536, aBase, bBase, sw0, sw1, acc);  // t+2 (buf2)
  }
  SYNC(4);
  stage_tile(aSrc + 62 * 64, bSrc + 62 * 64, (int8_t*)smem + 65536, ldsOff);
  compute_tile((const int8_t*)smem, aBase, bBase, sw0, sw1, acc);            // t60 (buf0)
  SYNC(4);
  stage_tile(aSrc + 63 * 64, bSrc + 63 * 64, (int8_t*)smem, ldsOff);
  compute_tile((const int8_t*)smem + 32768, aBase, bBase, sw0, sw1, acc);    // t61 (buf1)
  SYNC(4);
  compute_tile((const int8_t*)smem + 65536, aBase, bBase, sw0, sw1, acc);    // t62 (buf2)
  asm volatile("s_waitcnt vmcnt(0)" ::: "memory");
  __builtin_amdgcn_s_barrier();
  __builtin_amdgcn_sched_barrier(0);
  compute_tile((const int8_t*)smem, aBase, bBase, sw0, sw1, acc);            // t63 (buf0)

  // ---------------- epilogue: dequant + LoRA add ----------------
  asm volatile("s_waitcnt vmcnt(0) lgkmcnt(0)" ::: "memory");
  __syncthreads();                     // all DMAs/reads drained; reuse smem
  float* fs   = (float*)smem;
  float* xs_s = fs;                    // 256
  float* ws_s = fs + 256;              // 256
  float* xa_s = fs + 512;              // 256*8
  float* lb_s = fs + 2560;             // 256*8
  if (tid < 256) xs_s[tid] = x_scale[arow0 + tid];
  else           ws_s[tid - 256] = w_scale[brow0 + (tid - 256)];
  ((float4*)xa_s)[tid] = ((const float4*)(xa + arow0 * RANK))[tid];
  ((float4*)lb_s)[tid] = ((const float4*)(lora_b + brow0 * RANK))[tid];
  __syncthreads();

  float wscv[2];
  float4 lb0[2], lb1[2];
  int cols[2];
#pragma unroll
  for (int j = 0; j < 2; ++j) {
    const int c = wc * 64 + j * 32 + r31;          // C/D col = lane&31
    cols[j] = c;
    wscv[j] = ws_s[c];
    lb0[j] = *(const float4*)(lb_s + c * RANK);
    lb1[j] = *(const float4*)(lb_s + c * RANK + 4);
  }
#pragma unroll
  for (int i = 0; i < 4; ++i) {
#pragma unroll
    for (int reg = 0; reg < 16; ++reg) {
      // C/D row = (reg&3) + 8*(reg>>2) + 4*(lane>>5)   [m74/m101]
      const int r = wr * 128 + i * 32 + (reg & 3) + 8 * (reg >> 2) + 4 * khalf;
      const float xsc = xs_s[r];
      const float4 xa0 = *(const float4*)(xa_s + r * RANK);
      const float4 xa1 = *(const float4*)(xa_s + r * RANK + 4);
      float* orow = out + (arow0 + (size_t)r) * OUT_DIM + brow0;
#pragma unroll
      for (int j = 0; j < 2; ++j) {
        float v = (float)acc[i][j][reg] * xsc * wscv[j];
        v += xa0.x * lb0[j].x + xa0.y * lb0[j].y + xa0.z * lb0[j].z + xa0.w * lb0[j].w +
             xa1.x * lb1[j].x + xa1.y * lb1[j].y + xa1.z * lb1[j].z + xa1.w * lb1[j].w;
        orow[cols[j]] = v;
      }
    }
  }
}

// ---------------------------------------------------------------------------
extern "C" void kernel_launch(void* const* d_in, const int* in_sizes, int n_in,
                              void* d_out, int out_size, void* d_ws, size_t ws_size,
                              hipStream_t stream) {
  const float* x       = (const float*)d_in[0];
  const int*   w_i32   = (const int*)d_in[1];    // integer inputs upload as int32
  const float* w_scale = (const float*)d_in[2];
  const float* lora_a  = (const float*)d_in[3];
  const float* lora_b  = (const float*)d_in[4];
  float* out = (float*)d_out;

  // ws: x_i8 | w8 | x_scale[T] | xa[T][RANK]
  int8_t* x_i8    = (int8_t*)d_ws;
  int8_t* w8      = x_i8 + (size_t)T_DIM * IN_DIM;
  float*  x_scale = (float*)(w8 + (size_t)OUT_DIM * IN_DIM);
  float*  xa      = x_scale + T_DIM;

  pack_w<<<(OUT_DIM * IN_DIM / 4) / 256, 256, 0, stream>>>(w_i32, w8);
  quant_x<<<T_DIM / QROWS, 256, 0, stream>>>(x, lora_a, x_i8, x_scale, xa);
  gemm256_i8<<<(T_DIM / 256) * (OUT_DIM / 256), 512, 0, stream>>>(
      x_i8, w8, x_scale, w_scale, xa, lora_b, out);
}